// Round 15
// baseline (1822.475 us; speedup 1.0000x reference)
//
#include <hip/hip_runtime.h>
#include <cstdint>
#include <cstddef>

// ============================================================================
// ConditionalRBM sampler — bit-exact resimulation of the JAX reference.
//
// Round-15: two falsified theories (R13 occupancy, R14 I$) -> new model that
// retro-fits ALL rounds: v_cvt_f32_u32 on the quarter-rate trans pipe.
//   R12: (4cvt*8 + 20*2)*2waves = 144cy/k -> ~20us  (measured 23) ✓
//   R13: (32+26)*4waves = 232cy/k -> ~28-30us       (measured ~30) ✓
//   R4 (no cvt at all): the only kernel that ever matched its model ✓
// Fix (surgical, zero structural change from R14): bit->float via pure
// bit-ops: s = as_float(sext1(wd,kk) & 0x3f800000) = v_bfe_i32 + v_and_b32,
// 2 full-rate ops (4cy) vs bfe+cvt (2+8cy). Values bit-identical
// (1.0f / +0.0f), so the fma chain operands are unchanged.
// Everything else identical to R14 (best-known: bit-packed state, 64x64
// block, 4x4 tile, W-tile 64KiB in LDS staged once, masks 2KiB in LDS,
// zero in-loop global loads, kk unroll 8).
//
// ASSUMPTION STACK (verified bit-exact in earlier rounds):
//  A1: jax_threefry_partitionable = True:
//      split(key,n)[i] = TF(key,(0,i)); bits32[j] = TF0(key,(0,j)) ^ TF1(key,(0,j))
//  A2: logistic(x) = 1/(1+exp(-x)), IEEE fdiv
//  A3: exp = XLA-CPU vectorized Cephes/Eigen pexp
//  A4: dot = ascending-k single-accumulator fma chain (exact 0/1 products)
//  A5: x = (dot + udot) + bias association
//  Output dtype: int32 0/1 (harness reads d_out as int32).
//  Pack semantics (R12-verified): state word w of a row, bit b = col 32w+b.
// ============================================================================

#pragma clang fp contract(off)

#define BATCH 8192
#define NU 64
#define NF 256   // num_v == num_h == 256
#define BM 64    // rows per block in k_phase
#define BN 64    // cols per block in k_phase
#define RTI 16   // rows per block in k_init / k_udot
#define THERM 24
#define NSAMP 8

// ---------------- Threefry-2x32 (JAX rotation/injection schedule) ----------
__host__ __device__ __forceinline__ void tf2x32(uint32_t k0, uint32_t k1,
                                                uint32_t x0, uint32_t x1,
                                                uint32_t* o0, uint32_t* o1) {
  uint32_t ks2 = k0 ^ k1 ^ 0x1BD11BDAu;
  x0 += k0; x1 += k1;
#define TFR(r) { x0 += x1; x1 = (x1 << (r)) | (x1 >> (32 - (r))); x1 ^= x0; }
  TFR(13) TFR(15) TFR(26) TFR(6)
  x0 += k1;  x1 += ks2 + 1u;
  TFR(17) TFR(29) TFR(16) TFR(24)
  x0 += ks2; x1 += k0 + 2u;
  TFR(13) TFR(15) TFR(26) TFR(6)
  x0 += k0;  x1 += k1 + 3u;
  TFR(17) TFR(29) TFR(16) TFR(24)
  x0 += k1;  x1 += ks2 + 4u;
  TFR(13) TFR(15) TFR(26) TFR(6)
  x0 += ks2; x1 += k0 + 5u;
#undef TFR
  *o0 = x0; *o1 = x1;
}

// ---------------- XLA-CPU expf (Cephes/Eigen polynomial) -------------------
__device__ __forceinline__ float xla_expf(float x) {
  float xc = fminf(x, 88.3762626647950f);
  xc = fmaxf(xc, -88.3762626647949f);
  float fx = floorf(__builtin_fmaf(xc, 1.44269504088896341f, 0.5f));
  float tmp = 0.693359375f * fx;          // separate rounding (contract off)
  float z = -2.12194440e-4f * fx;
  float r = xc - tmp;
  r = r - z;
  z = r * r;
  float y = __builtin_fmaf(r, 1.9875691500e-4f, 1.3981999507e-3f);
  y = __builtin_fmaf(y, r, 8.3334519073e-3f);
  y = __builtin_fmaf(y, r, 4.1665795894e-2f);
  y = __builtin_fmaf(y, r, 1.6666665459e-1f);
  y = __builtin_fmaf(y, r, 5.0000001201e-1f);
  y = __builtin_fmaf(y, z, r);
  y = y + 1.0f;
  int n = (int)fx;
  float p2 = __int_as_float((n + 127) << 23);
  float res = y * p2;
  return fmaxf(res, x);                   // Eigen pexp: pmax(res, original x)
}

__device__ __forceinline__ float sigmoid_ref(float x) {
  float e = xla_expf(-x);                 // negate exact
  return 1.0f / (1.0f + e);               // IEEE fdiv (no fast-math)
}

// bern: partitionable threefry bits -> uniform [0,1) -> (u < p)
__device__ __forceinline__ float bern_sample(uint32_t key0, uint32_t key1,
                                             uint32_t idx, float p) {
  uint32_t b0, b1;
  tf2x32(key0, key1, 0u, idx, &b0, &b1);  // counter = (hi=0, lo=flat_idx)
  uint32_t bits = b0 ^ b1;                // 32-bit path XORs both words
  float u = __uint_as_float((bits >> 9) | 0x3f800000u) - 1.0f;
  return (u < p) ? 1.0f : 0.0f;
}

// bit kk of wd -> 1.0f / +0.0f with FULL-RATE ops only (no v_cvt):
// sign-extend the bit (v_bfe_i32) then AND with bits(1.0f) (v_and_b32).
__device__ __forceinline__ float bit_to_float(uint32_t wd, int kk) {
  int32_t se = ((int32_t)(wd << (31 - kk))) >> 31;   // 0 or 0xFFFFFFFF
  return __uint_as_float((uint32_t)se & 0x3f800000u);
}

// ---------------- kernels ---------------------------------------------------
__global__ void k_transpose(const float* __restrict__ Whv,
                            float* __restrict__ WhvT) {
  int j = threadIdx.x;  // hidden
  int k = blockIdx.x;   // visible
  WhvT[k * NF + j] = Whv[j * NF + k];
}

// out[row][j] = sum_k u[row][k] * W[j][k], ascending k (exact products).
__global__ __launch_bounds__(256, 2) void k_udot(const float* __restrict__ U,
                                                 const float* __restrict__ W,
                                                 float* __restrict__ out) {
  __shared__ __align__(16) float Ulds[NU * RTI];  // [k][i], 4 KiB
  const int j = threadIdx.x;
  const int i0 = blockIdx.x * RTI;
  const int si = j & 15;
  const int sg = j >> 4;
  {
    float4 u4 = *(const float4*)(U + (size_t)(i0 + si) * NU + sg * 4);
    Ulds[(sg * 4 + 0) * RTI + si] = u4.x;
    Ulds[(sg * 4 + 1) * RTI + si] = u4.y;
    Ulds[(sg * 4 + 2) * RTI + si] = u4.z;
    Ulds[(sg * 4 + 3) * RTI + si] = u4.w;
  }
  float wreg[NU];
  const float4* wr4 = (const float4*)(W + (size_t)j * NU);
#pragma unroll
  for (int r = 0; r < NU / 4; ++r) {
    float4 t = wr4[r];
    wreg[4 * r + 0] = t.x; wreg[4 * r + 1] = t.y;
    wreg[4 * r + 2] = t.z; wreg[4 * r + 3] = t.w;
  }
  __syncthreads();
  float acc[RTI];
#pragma unroll
  for (int i = 0; i < RTI; ++i) acc[i] = 0.0f;
#pragma unroll
  for (int kk = 0; kk < NU; ++kk) {
    const float w = wreg[kk];
    const float4 s0 = *(const float4*)(&Ulds[kk * RTI + 0]);
    const float4 s1 = *(const float4*)(&Ulds[kk * RTI + 4]);
    const float4 s2 = *(const float4*)(&Ulds[kk * RTI + 8]);
    const float4 s3 = *(const float4*)(&Ulds[kk * RTI + 12]);
    acc[0]  = __builtin_fmaf(s0.x, w, acc[0]);
    acc[1]  = __builtin_fmaf(s0.y, w, acc[1]);
    acc[2]  = __builtin_fmaf(s0.z, w, acc[2]);
    acc[3]  = __builtin_fmaf(s0.w, w, acc[3]);
    acc[4]  = __builtin_fmaf(s1.x, w, acc[4]);
    acc[5]  = __builtin_fmaf(s1.y, w, acc[5]);
    acc[6]  = __builtin_fmaf(s1.z, w, acc[6]);
    acc[7]  = __builtin_fmaf(s1.w, w, acc[7]);
    acc[8]  = __builtin_fmaf(s2.x, w, acc[8]);
    acc[9]  = __builtin_fmaf(s2.y, w, acc[9]);
    acc[10] = __builtin_fmaf(s2.z, w, acc[10]);
    acc[11] = __builtin_fmaf(s2.w, w, acc[11]);
    acc[12] = __builtin_fmaf(s3.x, w, acc[12]);
    acc[13] = __builtin_fmaf(s3.y, w, acc[13]);
    acc[14] = __builtin_fmaf(s3.z, w, acc[14]);
    acc[15] = __builtin_fmaf(s3.w, w, acc[15]);
  }
#pragma unroll
  for (int i = 0; i < RTI; ++i)
    out[(size_t)(i0 + i) * NF + j] = acc[i];   // row-major (coalesced)
}

// v0 = bern(ks[0], sigmoid(uv + bv)); emits PACKED state bits via ballot.
__global__ __launch_bounds__(256) void k_init(const float* __restrict__ uv,
                                              const float* __restrict__ bv,
                                              uint32_t* __restrict__ Vb,
                                              uint32_t key0, uint32_t key1) {
  const int j = threadIdx.x;
  const int i0 = blockIdx.x * RTI;
  const int wv = j >> 6, lane = j & 63;
  const float b = bv[j];
#pragma unroll
  for (int i = 0; i < RTI; ++i) {
    const int row = i0 + i;
    const uint32_t idx = (uint32_t)(row * NF + j);
    const float p = sigmoid_ref(uv[idx] + b);
    const float v = bern_sample(key0, key1, idx, p);
    unsigned long long m = __ballot(v != 0.0f);   // bit l = col 64*wv + l
    if (lane == 0)
      *(uint2*)(Vb + (size_t)row * 8 + 2 * wv) =
          make_uint2((uint32_t)m, (uint32_t)(m >> 32));
  }
}

// One Gibbs half-step: Ob = bern(key, sigmoid((S @ W) + C + bias)), packed.
// Sb: prev state bits [8192][8 words]; W: [256 k][256 j] k-major;
// C: u-dot [8192][256]; Ob: next-state bits; smp: optional int32 samples.
// Block 64x64, thread 4x4. W tile [256][64] = 64 KiB staged once; masks in
// LDS (2 KiB). Inner loop per k: 1 ds_read_b128 + 4x(bfe_i32+and) + 16 fma
// — ALL full-rate VALU (no v_cvt). kk unroll 8, wi rolled.
__global__ __launch_bounds__(256, 2) void k_phase(
    const uint32_t* __restrict__ Sb, const float* __restrict__ W,
    const float* __restrict__ C, const float* __restrict__ bias,
    uint32_t* __restrict__ Ob, int* __restrict__ smp,
    uint32_t key0, uint32_t key1) {
  __shared__ __align__(16) float Wlds[NF * BN];     // 64 KiB [k][c]
  __shared__ __align__(8) uint32_t Smask[BM * 8];   // 2 KiB [row][word]
  __shared__ uint32_t Nib[BM * 16];                 // 4 KiB nibble scratch
  const int t  = threadIdx.x;
  const int i0 = (blockIdx.x & 127) * BM;   // 128 row-blocks (consecutive ids
  const int c0 = (blockIdx.x >> 7) * BN;    //   share the same W col-slice)
  const int rg = t >> 4, cg = t & 15;
  const int jc = c0 + cg * 4;               // thread's 4 cols
  const int r0 = i0 + rg * 4;               // thread's 4 rows

  // stage masks: 64 rows x 8 words; thread t -> row t>>2, words (t&3)*2..+1
  {
    const int row = t >> 2, wo = (t & 3) * 2;
    *(uint2*)(&Smask[row * 8 + wo]) =
        *(const uint2*)(Sb + (size_t)(i0 + row) * 8 + wo);
  }
  // stage W tile in 4 batches of 4 float4 (bounded register pressure)
#pragma unroll
  for (int b = 0; b < 4; ++b) {
    float4 tmp0, tmp1, tmp2, tmp3;
    {
      const int f0 = (b * 4 + 0) * 256 + t;
      const int f1 = (b * 4 + 1) * 256 + t;
      const int f2 = (b * 4 + 2) * 256 + t;
      const int f3 = (b * 4 + 3) * 256 + t;
      tmp0 = *(const float4*)(W + (size_t)(f0 >> 4) * NF + c0 + (f0 & 15) * 4);
      tmp1 = *(const float4*)(W + (size_t)(f1 >> 4) * NF + c0 + (f1 & 15) * 4);
      tmp2 = *(const float4*)(W + (size_t)(f2 >> 4) * NF + c0 + (f2 & 15) * 4);
      tmp3 = *(const float4*)(W + (size_t)(f3 >> 4) * NF + c0 + (f3 & 15) * 4);
      *(float4*)(&Wlds[(size_t)(f0 >> 4) * BN + (f0 & 15) * 4]) = tmp0;
      *(float4*)(&Wlds[(size_t)(f1 >> 4) * BN + (f1 & 15) * 4]) = tmp1;
      *(float4*)(&Wlds[(size_t)(f2 >> 4) * BN + (f2 & 15) * 4]) = tmp2;
      *(float4*)(&Wlds[(size_t)(f3 >> 4) * BN + (f3 & 15) * 4]) = tmp3;
    }
  }
  __syncthreads();

  float acc[16];                      // acc[ri*4+ci]
#pragma unroll
  for (int q = 0; q < 16; ++q) acc[q] = 0.0f;

  const uint32_t* smrow = &Smask[(rg * 4) * 8];

#pragma unroll 1
  for (int wi = 0; wi < 8; ++wi) {    // 8 mask words = 8 x 32 k, ascending
    const uint32_t wd0 = smrow[0 * 8 + wi];
    const uint32_t wd1 = smrow[1 * 8 + wi];
    const uint32_t wd2 = smrow[2 * 8 + wi];
    const uint32_t wd3 = smrow[3 * 8 + wi];
    const float* wl = &Wlds[(wi * 32) * BN + cg * 4];
#pragma unroll 8
    for (int kk = 0; kk < 32; ++kk) {
      const float4 w = *(const float4*)(wl + kk * BN);   // 2-way/bcast: free
      const float s0 = bit_to_float(wd0, kk);            // 1.0f / +0.0f
      const float s1 = bit_to_float(wd1, kk);            // (full-rate ops)
      const float s2 = bit_to_float(wd2, kk);
      const float s3 = bit_to_float(wd3, kk);
      acc[0]  = __builtin_fmaf(s0, w.x, acc[0]);   // exact products
      acc[1]  = __builtin_fmaf(s0, w.y, acc[1]);
      acc[2]  = __builtin_fmaf(s0, w.z, acc[2]);
      acc[3]  = __builtin_fmaf(s0, w.w, acc[3]);
      acc[4]  = __builtin_fmaf(s1, w.x, acc[4]);
      acc[5]  = __builtin_fmaf(s1, w.y, acc[5]);
      acc[6]  = __builtin_fmaf(s1, w.z, acc[6]);
      acc[7]  = __builtin_fmaf(s1, w.w, acc[7]);
      acc[8]  = __builtin_fmaf(s2, w.x, acc[8]);
      acc[9]  = __builtin_fmaf(s2, w.y, acc[9]);
      acc[10] = __builtin_fmaf(s2, w.z, acc[10]);
      acc[11] = __builtin_fmaf(s2, w.w, acc[11]);
      acc[12] = __builtin_fmaf(s3, w.x, acc[12]);
      acc[13] = __builtin_fmaf(s3, w.y, acc[13]);
      acc[14] = __builtin_fmaf(s3, w.z, acc[14]);
      acc[15] = __builtin_fmaf(s3, w.w, acc[15]);
    }
  }

  // epilogue: x = (dot + udot) + bias ; p = sigmoid ; bern
  const float4 b4 = *(const float4*)(bias + jc);
  float vals[16];
#pragma unroll
  for (int ri = 0; ri < 4; ++ri) {
    const int row = r0 + ri;
    const float4 c4 = *(const float4*)(C + (size_t)row * NF + jc);
    const uint32_t idx0 = (uint32_t)(row * NF + jc);
    vals[ri * 4 + 0] = bern_sample(key0, key1, idx0 + 0,
        sigmoid_ref((acc[ri * 4 + 0] + c4.x) + b4.x));
    vals[ri * 4 + 1] = bern_sample(key0, key1, idx0 + 1,
        sigmoid_ref((acc[ri * 4 + 1] + c4.y) + b4.y));
    vals[ri * 4 + 2] = bern_sample(key0, key1, idx0 + 2,
        sigmoid_ref((acc[ri * 4 + 2] + c4.z) + b4.z));
    vals[ri * 4 + 3] = bern_sample(key0, key1, idx0 + 3,
        sigmoid_ref((acc[ri * 4 + 3] + c4.w) + b4.w));
  }

  // int32 sample output (row-major)
  if (smp) {
#pragma unroll
    for (int ri = 0; ri < 4; ++ri) {
      const int row = r0 + ri;
      int4 o;
      o.x = (vals[ri * 4 + 0] != 0.0f) ? 1 : 0;
      o.y = (vals[ri * 4 + 1] != 0.0f) ? 1 : 0;
      o.z = (vals[ri * 4 + 2] != 0.0f) ? 1 : 0;
      o.w = (vals[ri * 4 + 3] != 0.0f) ? 1 : 0;
      *(int4*)(smp + (size_t)row * NF + jc) = o;
    }
  }

  // packed next-state: nibble per (row, cg) -> LDS -> word assembly
#pragma unroll
  for (int ri = 0; ri < 4; ++ri) {
    uint32_t nb = (vals[ri * 4 + 0] != 0.0f ? 1u : 0u) |
                  (vals[ri * 4 + 1] != 0.0f ? 2u : 0u) |
                  (vals[ri * 4 + 2] != 0.0f ? 4u : 0u) |
                  (vals[ri * 4 + 3] != 0.0f ? 8u : 0u);
    Nib[(rg * 4 + ri) * 16 + cg] = nb;
  }
  __syncthreads();
  if (t < 128) {                       // 2 words per row: 64 rows x 2
    const int row = t >> 1, half = t & 1;
    const uint32_t* nb = &Nib[row * 16 + half * 8];
    uint32_t wrd = nb[0] | (nb[1] << 4) | (nb[2] << 8) | (nb[3] << 12) |
                   (nb[4] << 16) | (nb[5] << 20) | (nb[6] << 24) | (nb[7] << 28);
    Ob[(size_t)(i0 + row) * 8 + (c0 >> 5) + half] = wrd;
  }
}

// ---------------- launch ----------------------------------------------------
extern "C" void kernel_launch(void* const* d_in, const int* in_sizes, int n_in,
                              void* d_out, int out_size, void* d_ws, size_t ws_size,
                              hipStream_t stream) {
  const float* u_state = (const float*)d_in[0];  // [8192][64] 0/1 floats
  const float* Wvu     = (const float*)d_in[1];  // [256][64]
  const float* Whu     = (const float*)d_in[2];  // [256][64]
  const float* Whv     = (const float*)d_in[3];  // [256][256]
  const float* bv      = (const float*)d_in[4];  // [256]
  const float* bh      = (const float*)d_in[5];  // [256]
  int* out = (int*)d_out;                        // [8][8192][256] as int32 0/1

  // workspace layout: WhvT 256KB, uh/uv 8MB each, Vb/Hb 256KB each (~17.3MB)
  float* ws   = (float*)d_ws;
  float* WhvT = ws;                          // 65536 f
  float* uh   = WhvT + NF * NF;              // [8192][256]
  float* uv   = uh + (size_t)BATCH * NF;
  uint32_t* Vb = (uint32_t*)(uv + (size_t)BATCH * NF);  // [8192][8]
  uint32_t* Hb = Vb + (size_t)BATCH * 8;                // [8192][8]

  // ---- host-side key schedule (pure CPU, deterministic) ----
  uint32_t s0[THERM + NSAMP + 1], s1[THERM + NSAMP + 1];
  for (uint32_t i = 0; i < THERM + NSAMP + 1; ++i)
    tf2x32(0u, 1u, 0u, i, &s0[i], &s1[i]);

  k_transpose<<<NF, NF, 0, stream>>>(Whv, WhvT);
  k_udot<<<BATCH / RTI, NF, 0, stream>>>(u_state, Whu, uh);   // u @ Whu.T
  k_udot<<<BATCH / RTI, NF, 0, stream>>>(u_state, Wvu, uv);   // u @ Wvu.T
  k_init<<<BATCH / RTI, NF, 0, stream>>>(uv, bv, Vb, s0[0], s1[0]);

  const int phase_blocks = (BATCH / BM) * (NF / BN);   // 128 * 4 = 512
  for (int t = 0; t < THERM + NSAMP; ++t) {
    uint32_t kh0, kh1, kv0, kv1;
    tf2x32(s0[1 + t], s1[1 + t], 0u, 0u, &kh0, &kh1);
    tf2x32(s0[1 + t], s1[1 + t], 0u, 1u, &kv0, &kv1);
    int* smp = (t >= THERM) ? out + (size_t)(t - THERM) * BATCH * NF : (int*)nullptr;
    // h = bern(k1, sigmoid(v @ Whv.T + uh + bh))
    k_phase<<<phase_blocks, NF, 0, stream>>>(Vb, WhvT, uh, bh, Hb, (int*)nullptr, kh0, kh1);
    // v = bern(k2, sigmoid(h @ Whv + uv + bv)) ; emit sample when t>=THERM
    k_phase<<<phase_blocks, NF, 0, stream>>>(Hb, Whv, uv, bv, Vb, smp, kv0, kv1);
  }
  (void)in_sizes; (void)n_in; (void)out_size; (void)ws_size;
}

// Round 16
// 1654.813 us; speedup vs baseline: 1.1013x; 1.1013x over previous
//
#include <hip/hip_runtime.h>
#include <cstdint>
#include <cstddef>

// ============================================================================
// ConditionalRBM sampler — bit-exact resimulation of the JAX reference.
//
// Round-16: STRUCTURAL pivot. The Gibbs chain is ROW-INDEPENDENT:
// v[i] <- h[i] <- v[i] uses only row i's state (weights shared). So a block
// owning 16 rows runs ALL 65 phases internally with __syncthreads() only —
// the 64 dependent launches (ramp/drain, W re-stage, mask global round-trips)
// were structurally unnecessary.
//  - grid 512 x 256 thr (16 rows/block), 2 blocks/CU (73.5 KB LDS)
//  - staged once per block: uh/uv slices (32 KB), biases, full threefry key
//    schedule (computed in-kernel); state bits (1 KB) resident in LDS
//  - per phase: W (WhvT for h, Whv for v) staged in 16-row chunks via
//    __builtin_amdgcn_global_load_lds(16B), double-buffered, T3 discipline:
//    stage(c+1); compute(c); __syncthreads(). Only vmem in flight = the
//    prefetch -> the barrier drain lands after ~600cy of compute cover.
//    (gload_lds uses no registers -> nothing for the scheduler to sink,
//    sidestepping the R7/R9/R10 failures.)
//  - inner loop: R12/R14's proven body verbatim (1 ds_read_b128 + 4 bfe+cvt
//    + 16 fma per k), k = c*16+kk strictly ascending, single accumulator.
//
// ASSUMPTION STACK (verified bit-exact in earlier rounds):
//  A1: jax_threefry_partitionable = True:
//      split(key,n)[i] = TF(key,(0,i)); bits32[j] = TF0(key,(0,j)) ^ TF1(key,(0,j))
//  A2: logistic(x) = 1/(1+exp(-x)), IEEE fdiv
//  A3: exp = XLA-CPU vectorized Cephes/Eigen pexp
//  A4: dot = ascending-k single-accumulator fma chain (exact 0/1 products)
//  A5: x = (dot + udot) + bias association
//  Output dtype: int32 0/1 (harness reads d_out as int32).
//  Pack semantics (R12-verified): state word w of a row, bit b = col 32w+b.
// ============================================================================

#pragma clang fp contract(off)

#define BATCH 8192
#define NU 64
#define NF 256   // num_v == num_h == 256
#define RPB 16   // rows per block (chain kernel)
#define CH 16    // m-rows per staged W chunk
#define NCH (NF / CH)   // 16 chunks per phase
#define RTI 16   // rows per block in k_udot
#define THERM 24
#define NSAMP 8
#define NSTEP (THERM + NSAMP)   // 32 Gibbs steps

// ---------------- Threefry-2x32 (JAX rotation/injection schedule) ----------
__host__ __device__ __forceinline__ void tf2x32(uint32_t k0, uint32_t k1,
                                                uint32_t x0, uint32_t x1,
                                                uint32_t* o0, uint32_t* o1) {
  uint32_t ks2 = k0 ^ k1 ^ 0x1BD11BDAu;
  x0 += k0; x1 += k1;
#define TFR(r) { x0 += x1; x1 = (x1 << (r)) | (x1 >> (32 - (r))); x1 ^= x0; }
  TFR(13) TFR(15) TFR(26) TFR(6)
  x0 += k1;  x1 += ks2 + 1u;
  TFR(17) TFR(29) TFR(16) TFR(24)
  x0 += ks2; x1 += k0 + 2u;
  TFR(13) TFR(15) TFR(26) TFR(6)
  x0 += k0;  x1 += k1 + 3u;
  TFR(17) TFR(29) TFR(16) TFR(24)
  x0 += k1;  x1 += ks2 + 4u;
  TFR(13) TFR(15) TFR(26) TFR(6)
  x0 += ks2; x1 += k0 + 5u;
#undef TFR
  *o0 = x0; *o1 = x1;
}

// ---------------- XLA-CPU expf (Cephes/Eigen polynomial) -------------------
__device__ __forceinline__ float xla_expf(float x) {
  float xc = fminf(x, 88.3762626647950f);
  xc = fmaxf(xc, -88.3762626647949f);
  float fx = floorf(__builtin_fmaf(xc, 1.44269504088896341f, 0.5f));
  float tmp = 0.693359375f * fx;          // separate rounding (contract off)
  float z = -2.12194440e-4f * fx;
  float r = xc - tmp;
  r = r - z;
  z = r * r;
  float y = __builtin_fmaf(r, 1.9875691500e-4f, 1.3981999507e-3f);
  y = __builtin_fmaf(y, r, 8.3334519073e-3f);
  y = __builtin_fmaf(y, r, 4.1665795894e-2f);
  y = __builtin_fmaf(y, r, 1.6666665459e-1f);
  y = __builtin_fmaf(y, r, 5.0000001201e-1f);
  y = __builtin_fmaf(y, z, r);
  y = y + 1.0f;
  int n = (int)fx;
  float p2 = __int_as_float((n + 127) << 23);
  float res = y * p2;
  return fmaxf(res, x);                   // Eigen pexp: pmax(res, original x)
}

__device__ __forceinline__ float sigmoid_ref(float x) {
  float e = xla_expf(-x);                 // negate exact
  return 1.0f / (1.0f + e);               // IEEE fdiv (no fast-math)
}

// bern: partitionable threefry bits -> uniform [0,1) -> (u < p)
__device__ __forceinline__ float bern_sample(uint32_t key0, uint32_t key1,
                                             uint32_t idx, float p) {
  uint32_t b0, b1;
  tf2x32(key0, key1, 0u, idx, &b0, &b1);  // counter = (hi=0, lo=flat_idx)
  uint32_t bits = b0 ^ b1;                // 32-bit path XORs both words
  float u = __uint_as_float((bits >> 9) | 0x3f800000u) - 1.0f;
  return (u < p) ? 1.0f : 0.0f;
}

// async global->LDS, 16 bytes per lane (linear layout: dest = base+lane*16)
__device__ __forceinline__ void gld_lds16(const float* g, float* l) {
  __builtin_amdgcn_global_load_lds(
      (const __attribute__((address_space(1))) void*)g,
      (__attribute__((address_space(3))) void*)l, 16, 0, 0);
}

// ---------------- kernels ---------------------------------------------------
__global__ void k_transpose(const float* __restrict__ Whv,
                            float* __restrict__ WhvT) {
  int j = threadIdx.x;  // hidden
  int k = blockIdx.x;   // visible
  WhvT[k * NF + j] = Whv[j * NF + k];
}

// out[row][j] = sum_k u[row][k] * W[j][k], ascending k (exact products).
__global__ __launch_bounds__(256, 2) void k_udot(const float* __restrict__ U,
                                                 const float* __restrict__ W,
                                                 float* __restrict__ out) {
  __shared__ __align__(16) float Ulds[NU * RTI];  // [k][i], 4 KiB
  const int j = threadIdx.x;
  const int i0 = blockIdx.x * RTI;
  const int si = j & 15;
  const int sg = j >> 4;
  {
    float4 u4 = *(const float4*)(U + (size_t)(i0 + si) * NU + sg * 4);
    Ulds[(sg * 4 + 0) * RTI + si] = u4.x;
    Ulds[(sg * 4 + 1) * RTI + si] = u4.y;
    Ulds[(sg * 4 + 2) * RTI + si] = u4.z;
    Ulds[(sg * 4 + 3) * RTI + si] = u4.w;
  }
  float wreg[NU];
  const float4* wr4 = (const float4*)(W + (size_t)j * NU);
#pragma unroll
  for (int r = 0; r < NU / 4; ++r) {
    float4 t = wr4[r];
    wreg[4 * r + 0] = t.x; wreg[4 * r + 1] = t.y;
    wreg[4 * r + 2] = t.z; wreg[4 * r + 3] = t.w;
  }
  __syncthreads();
  float acc[RTI];
#pragma unroll
  for (int i = 0; i < RTI; ++i) acc[i] = 0.0f;
#pragma unroll
  for (int kk = 0; kk < NU; ++kk) {
    const float w = wreg[kk];
    const float4 s0 = *(const float4*)(&Ulds[kk * RTI + 0]);
    const float4 s1 = *(const float4*)(&Ulds[kk * RTI + 4]);
    const float4 s2 = *(const float4*)(&Ulds[kk * RTI + 8]);
    const float4 s3 = *(const float4*)(&Ulds[kk * RTI + 12]);
    acc[0]  = __builtin_fmaf(s0.x, w, acc[0]);
    acc[1]  = __builtin_fmaf(s0.y, w, acc[1]);
    acc[2]  = __builtin_fmaf(s0.z, w, acc[2]);
    acc[3]  = __builtin_fmaf(s0.w, w, acc[3]);
    acc[4]  = __builtin_fmaf(s1.x, w, acc[4]);
    acc[5]  = __builtin_fmaf(s1.y, w, acc[5]);
    acc[6]  = __builtin_fmaf(s1.z, w, acc[6]);
    acc[7]  = __builtin_fmaf(s1.w, w, acc[7]);
    acc[8]  = __builtin_fmaf(s2.x, w, acc[8]);
    acc[9]  = __builtin_fmaf(s2.y, w, acc[9]);
    acc[10] = __builtin_fmaf(s2.z, w, acc[10]);
    acc[11] = __builtin_fmaf(s2.w, w, acc[11]);
    acc[12] = __builtin_fmaf(s3.x, w, acc[12]);
    acc[13] = __builtin_fmaf(s3.y, w, acc[13]);
    acc[14] = __builtin_fmaf(s3.z, w, acc[14]);
    acc[15] = __builtin_fmaf(s3.w, w, acc[15]);
  }
#pragma unroll
  for (int i = 0; i < RTI; ++i)
    out[(size_t)(i0 + i) * NF + j] = acc[i];   // row-major (coalesced)
}

// Whole Gibbs chain for 16 rows: init + 32 steps (h,v), samples to out.
__global__ __launch_bounds__(256, 2) void k_chain(
    const float* __restrict__ Whv, const float* __restrict__ WhvT,
    const float* __restrict__ uh, const float* __restrict__ uv,
    const float* __restrict__ bh, const float* __restrict__ bv,
    int* __restrict__ out) {
  __shared__ __align__(16) float Wbuf[2][CH * NF];   // 2 x 16 KiB
  __shared__ __align__(16) float Cu[2][RPB * NF];    // [0]=uh [1]=uv, 32 KiB
  __shared__ uint32_t bitsL[2][RPB * 8];             // [0]=v [1]=h, 1 KiB
  __shared__ uint32_t nib[RPB * 64];                 // 4 KiB pack scratch
  __shared__ float biasL[2][NF];                     // [0]=bh [1]=bv, 2 KiB
  __shared__ uint32_t ksL[66];                       // 33 key pairs
  __shared__ uint32_t keysL[NSTEP * 4];              // (kh0,kh1,kv0,kv1)/step

  const int t = threadIdx.x;
  const int rowbase = blockIdx.x * RPB;
  const int rg = t & 3;          // 4 row-groups x 4 rows (16 rows)
  const int cgg = t >> 2;        // 64 col-groups x 4 cols
  const int jc = cgg * 4;        // thread's first col

  // ---- prologue: stage uh/uv slices, biases, key schedule ----
  {
    const float4* gu = (const float4*)(uh + (size_t)rowbase * NF);
    const float4* gv = (const float4*)(uv + (size_t)rowbase * NF);
    float4* lu = (float4*)Cu[0];
    float4* lv = (float4*)Cu[1];
#pragma unroll
    for (int q = 0; q < 4; ++q) {
      lu[q * 256 + t] = gu[q * 256 + t];
      lv[q * 256 + t] = gv[q * 256 + t];
    }
    biasL[0][t] = bh[t];
    biasL[1][t] = bv[t];
    if (t < 33) tf2x32(0u, 1u, 0u, (uint32_t)t, &ksL[2 * t], &ksL[2 * t + 1]);
  }
  __syncthreads();
  if (t < NSTEP) {
    uint32_t a = ksL[2 * (1 + t)], b2 = ksL[2 * (1 + t) + 1];
    tf2x32(a, b2, 0u, 0u, &keysL[4 * t + 0], &keysL[4 * t + 1]);
    tf2x32(a, b2, 0u, 1u, &keysL[4 * t + 2], &keysL[4 * t + 3]);
  }
  __syncthreads();

  // ---- init: v0 = bern(ks[0], sigmoid(uv + bv)) -> bitsL[0] ----
  {
    const uint32_t k0 = ksL[0], k1 = ksL[1];
#pragma unroll
    for (int ri = 0; ri < 4; ++ri) {
      const int lr = rg * 4 + ri;
      const int row = rowbase + lr;
      uint32_t nb = 0;
#pragma unroll
      for (int ci = 0; ci < 4; ++ci) {
        const int j = jc + ci;
        const float x = Cu[1][lr * NF + j] + biasL[1][j];   // uv + bv
        const float v = bern_sample(k0, k1, (uint32_t)(row * NF + j),
                                    sigmoid_ref(x));
        nb |= (v != 0.0f ? 1u : 0u) << ci;
      }
      nib[lr * 64 + cgg] = nb;
    }
  }
  __syncthreads();
  if (t < 128) {
    const int lr = t >> 3, wo = t & 7;
    const uint32_t* nn = &nib[lr * 64 + wo * 8];
    uint32_t wrd = 0;
#pragma unroll
    for (int g = 0; g < 8; ++g) wrd |= nn[g] << (4 * g);
    bitsL[0][lr * 8 + wo] = wrd;
  }
  __syncthreads();

  // ---- Gibbs chain: 32 steps x (h-phase, v-phase) ----
#pragma unroll 1
  for (int tt = 0; tt < NSTEP; ++tt) {
#pragma unroll 1
    for (int ph = 0; ph < 2; ++ph) {
      const float* M = ph ? Whv : WhvT;          // reduction index = M row
      const uint32_t* sb = bitsL[ph];            // ph=0 reads v, ph=1 reads h
      uint32_t* db = bitsL[ph ^ 1];
      const float* Cl = Cu[ph];                  // ph=0: uh ; ph=1: uv
      const float* bl = biasL[ph];
      const uint32_t k0 = keysL[4 * tt + 2 * ph + 0];
      const uint32_t k1 = keysL[4 * tt + 2 * ph + 1];
      int* smp = (ph == 1 && tt >= THERM)
                     ? out + (size_t)(tt - THERM) * BATCH * NF
                     : (int*)nullptr;

      float acc[16];
#pragma unroll
      for (int q = 0; q < 16; ++q) acc[q] = 0.0f;

      // stage chunk 0 (async, no registers)
#pragma unroll
      for (int q = 0; q < 4; ++q)
        gld_lds16(M + (size_t)(q * 256 + t) * 4, &Wbuf[0][(q * 256 + t) * 4]);
      __syncthreads();   // drains vmcnt -> chunk 0 landed

#pragma unroll 1
      for (int c = 0; c < NCH; ++c) {
        if (c + 1 < NCH) {                       // prefetch next chunk
          const float* src = M + (size_t)(c + 1) * CH * NF;
          float* dst = Wbuf[(c + 1) & 1];
#pragma unroll
          for (int q = 0; q < 4; ++q)
            gld_lds16(src + (size_t)(q * 256 + t) * 4,
                      &dst[(q * 256 + t) * 4]);
        }
        const int wi = c >> 1;
        const int hs = (c & 1) * 16;             // which half of the word
        const uint32_t wd0 = sb[(rg * 4 + 0) * 8 + wi] >> hs;
        const uint32_t wd1 = sb[(rg * 4 + 1) * 8 + wi] >> hs;
        const uint32_t wd2 = sb[(rg * 4 + 2) * 8 + wi] >> hs;
        const uint32_t wd3 = sb[(rg * 4 + 3) * 8 + wi] >> hs;
        const float* wl = &Wbuf[c & 1][jc];
#pragma unroll
        for (int kk = 0; kk < CH; ++kk) {        // m = c*16+kk, ascending
          const float4 w = *(const float4*)(wl + kk * NF);
          const float s0 = (float)((wd0 >> kk) & 1u);   // 1.0f / +0.0f
          const float s1 = (float)((wd1 >> kk) & 1u);
          const float s2 = (float)((wd2 >> kk) & 1u);
          const float s3 = (float)((wd3 >> kk) & 1u);
          acc[0]  = __builtin_fmaf(s0, w.x, acc[0]);    // exact products
          acc[1]  = __builtin_fmaf(s0, w.y, acc[1]);
          acc[2]  = __builtin_fmaf(s0, w.z, acc[2]);
          acc[3]  = __builtin_fmaf(s0, w.w, acc[3]);
          acc[4]  = __builtin_fmaf(s1, w.x, acc[4]);
          acc[5]  = __builtin_fmaf(s1, w.y, acc[5]);
          acc[6]  = __builtin_fmaf(s1, w.z, acc[6]);
          acc[7]  = __builtin_fmaf(s1, w.w, acc[7]);
          acc[8]  = __builtin_fmaf(s2, w.x, acc[8]);
          acc[9]  = __builtin_fmaf(s2, w.y, acc[9]);
          acc[10] = __builtin_fmaf(s2, w.z, acc[10]);
          acc[11] = __builtin_fmaf(s2, w.w, acc[11]);
          acc[12] = __builtin_fmaf(s3, w.x, acc[12]);
          acc[13] = __builtin_fmaf(s3, w.y, acc[13]);
          acc[14] = __builtin_fmaf(s3, w.z, acc[14]);
          acc[15] = __builtin_fmaf(s3, w.w, acc[15]);
        }
        __syncthreads();   // chunk c+1 landed; all done reading buf[c&1]
      }

      // epilogue: x = (dot + udot) + bias ; sigmoid ; bern ; pack bits
      const float4 b4 = *(const float4*)(bl + jc);
#pragma unroll
      for (int ri = 0; ri < 4; ++ri) {
        const int lr = rg * 4 + ri;
        const int row = rowbase + lr;
        const float4 c4 = *(const float4*)(Cl + lr * NF + jc);
        const uint32_t idx0 = (uint32_t)(row * NF + jc);
        const float v0 = bern_sample(k0, k1, idx0 + 0,
            sigmoid_ref((acc[ri * 4 + 0] + c4.x) + b4.x));
        const float v1 = bern_sample(k0, k1, idx0 + 1,
            sigmoid_ref((acc[ri * 4 + 1] + c4.y) + b4.y));
        const float v2 = bern_sample(k0, k1, idx0 + 2,
            sigmoid_ref((acc[ri * 4 + 2] + c4.z) + b4.z));
        const float v3 = bern_sample(k0, k1, idx0 + 3,
            sigmoid_ref((acc[ri * 4 + 3] + c4.w) + b4.w));
        nib[lr * 64 + cgg] = (v0 != 0.0f ? 1u : 0u) |
                             (v1 != 0.0f ? 2u : 0u) |
                             (v2 != 0.0f ? 4u : 0u) |
                             (v3 != 0.0f ? 8u : 0u);
        if (smp) {
          int4 o;
          o.x = (v0 != 0.0f) ? 1 : 0;
          o.y = (v1 != 0.0f) ? 1 : 0;
          o.z = (v2 != 0.0f) ? 1 : 0;
          o.w = (v3 != 0.0f) ? 1 : 0;
          *(int4*)(smp + (size_t)row * NF + jc) = o;
        }
      }
      __syncthreads();
      if (t < 128) {                 // assemble 2 words per row
        const int lr = t >> 3, wo = t & 7;
        const uint32_t* nn = &nib[lr * 64 + wo * 8];
        uint32_t wrd = 0;
#pragma unroll
        for (int g = 0; g < 8; ++g) wrd |= nn[g] << (4 * g);
        db[lr * 8 + wo] = wrd;
      }
      __syncthreads();
    }
  }
}

// ---------------- launch ----------------------------------------------------
extern "C" void kernel_launch(void* const* d_in, const int* in_sizes, int n_in,
                              void* d_out, int out_size, void* d_ws, size_t ws_size,
                              hipStream_t stream) {
  const float* u_state = (const float*)d_in[0];  // [8192][64] 0/1 floats
  const float* Wvu     = (const float*)d_in[1];  // [256][64]
  const float* Whu     = (const float*)d_in[2];  // [256][64]
  const float* Whv     = (const float*)d_in[3];  // [256][256]
  const float* bv      = (const float*)d_in[4];  // [256]
  const float* bh      = (const float*)d_in[5];  // [256]
  int* out = (int*)d_out;                        // [8][8192][256] as int32 0/1

  // workspace: WhvT 256KB + uh 8MB + uv 8MB = ~16.8 MB
  float* ws   = (float*)d_ws;
  float* WhvT = ws;                          // 65536 f
  float* uh   = WhvT + NF * NF;              // [8192][256]
  float* uv   = uh + (size_t)BATCH * NF;

  k_transpose<<<NF, NF, 0, stream>>>(Whv, WhvT);
  k_udot<<<BATCH / RTI, NF, 0, stream>>>(u_state, Whu, uh);   // u @ Whu.T
  k_udot<<<BATCH / RTI, NF, 0, stream>>>(u_state, Wvu, uv);   // u @ Wvu.T
  // whole Gibbs chain in ONE launch (row-independent blocks)
  k_chain<<<BATCH / RPB, NF, 0, stream>>>(Whv, WhvT, uh, uv, bh, bv, out);

  (void)in_sizes; (void)n_in; (void)out_size; (void)ws_size;
}